// Round 14
// baseline (154.975 us; speedup 1.0000x reference)
//
#include <hip/hip_runtime.h>

// SSIM 3D, round 17 = round 16 (4-field + symmetric weights, VGPR=56, 32
// waves/CU = HW max residency, main ~57 µs, wall 151.6) + two conservative
// shavings inside the proven shape:
//  1. Paired-plane LDS layout: planes {m1,m2} and {qs,q12}, [2][8][132][2]
//     (+4-col pad -> ~2-way banks, free per m136). Writes stay 4x b128/phase;
//     H-conv reads HALVE: 20x b64 -> 10x b128 (one read = both fields, both
//     cols). -10 DS issue slots and -10 latency events per phase on the
//     intra-wave W->write->read->H serial chain.
//  2. factorize_window fused into ssim_main: weights recomputed per block
//     (9 loads + 6 divides, wave-uniform, bit-identical); 3 launches -> 2.
// Everything else verbatim r16: barrier-free wave-private LDS + asm fences,
// 2x5-phase loop + 2-phase tail, (256,2), plain partials tail + finalize.
// TLP is structurally maxed (2048 blk x 4 waves = 32 waves/CU); this round
// attacks the remaining ~34% issue gap. If neutral => issue-bound at max
// residency => declare practical ceiling.
// Tripwires: VGPR <= 64 (else revert); SQ_LDS_BANK_CONFLICT < 1M (else pad
// wrong, revert); WRITE_SIZE < 1 MB (spill detector; VGPR_Count lies).
// Tile: W=128 (4 waves x 32 cols), TH=4 rows, DSUB=8 -> 2048 blocks.

#define NDIM 128
#define TH 4
#define WR (TH + 4)            // 8 W-conv rows
#define DSUB 8
#define NHT (NDIM / TH)        // 32
#define NDT (NDIM / DSUB)      // 16
#define NB 4
#define NBLK (NHT * NDT * NB)  // 2048
#define PADC 4                 // LDS col pad: row stride 132 pairs -> ~2-way banks

__launch_bounds__(256, 2)
__global__ void ssim_main(const float* __restrict__ img1,
                          const float* __restrict__ img2,
                          const float* __restrict__ win,
                          float* __restrict__ partials) {
    const int bid = blockIdx.x;
    const int th = bid % NHT;
    const int td = (bid / NHT) % NDT;
    const int b  = bid / (NHT * NDT);

    const int h0 = th * TH, d0 = td * DSUB;
    const float* __restrict__ x1 = img1 + (size_t)(b * 2 + 1) * NDIM * NDIM * NDIM;
    const float* __restrict__ x2 = img2 + (size_t)b * NDIM * NDIM * NDIM;

    // Symmetric rank-1 window factors, computed per block (wave-uniform,
    // bit-identical to the old factorize kernel; taps 3,4 == 1,0).
    const float w000 = win[0];
    float uW[3], vW[3], tW[3];
    #pragma unroll
    for (int i = 0; i < 3; ++i) {
        uW[i] = win[i * 25];
        vW[i] = win[i * 5] / w000;
        tW[i] = win[i] / w000;
    }

    // Paired planes: sP[0] = {m1,m2} per col, sP[1] = {qs,q12} per col.
    __shared__ float sP[2][WR][NDIM + PADC][2];   // 16896 B
    __shared__ float sRed[4];

    const int tid  = threadIdx.x;
    const int wv   = tid >> 6;           // wave id 0..3 -> col stripe
    const int lane = tid & 63;
    const int sc   = wv * 32;            // stripe col base
    // W-conv mapping (per wave): 8 rows x 8 col-groups of 4
    const int wrow = lane >> 3;          // 0..7
    const int wg   = lane & 7;           // 0..7
    const int c0   = sc + wg * 4;        // col of this lane's 4 outputs
    const int ghw  = h0 + wrow - 2;
    // H/D mapping (per wave): 4 rows x 16 col-pairs of 2
    const int orow = lane >> 4;          // 0..3
    const int oc   = sc + (lane & 15) * 2;

    float2 ring[5][4];                   // [slot][field: m1,m2,qs,q12]
    float2 accS = make_float2(0.f, 0.f);

#define PHASE(I, P) do {                                                       \
    const int i_ = (I);                                                        \
    const int d_ = d0 - 2 + i_;                                                \
    float4 A0 = make_float4(0,0,0,0), A1 = A0, A2 = A0;                        \
    float4 B0 = A0, B1 = A0, B2 = A0;                                          \
    if (((unsigned)d_ < NDIM) && ((unsigned)ghw < NDIM)) {                     \
        const float* __restrict__ r1_ = x1 + ((size_t)d_ * NDIM + ghw) * NDIM; \
        const float* __restrict__ r2_ = x2 + ((size_t)d_ * NDIM + ghw) * NDIM; \
        if (c0 > 0)   { A0 = *(const float4*)(r1_ + c0 - 4);                   \
                        B0 = *(const float4*)(r2_ + c0 - 4); }                 \
        A1 = *(const float4*)(r1_ + c0);                                       \
        B1 = *(const float4*)(r2_ + c0);                                       \
        if (c0 < 124) { A2 = *(const float4*)(r1_ + c0 + 4);                   \
                        B2 = *(const float4*)(r2_ + c0 + 4); }                 \
    }                                                                          \
    float ra[12] = {A0.x,A0.y,A0.z,A0.w, A1.x,A1.y,A1.z,A1.w,                  \
                    A2.x,A2.y,A2.z,A2.w};                                      \
    float rb[12] = {B0.x,B0.y,B0.z,B0.w, B1.x,B1.y,B1.z,B1.w,                  \
                    B2.x,B2.y,B2.z,B2.w};                                      \
    float m1v[4], m2v[4], qsv[4], q12v[4];                                     \
    _Pragma("unroll")                                                          \
    for (int k_ = 0; k_ < 4; ++k_) {                                           \
        const float a0_=ra[k_+2], a1_=ra[k_+3], a2_=ra[k_+4],                  \
                    a3_=ra[k_+5], a4_=ra[k_+6];                                \
        const float b0_=rb[k_+2], b1_=rb[k_+3], b2_=rb[k_+4],                  \
                    b3_=rb[k_+5], b4_=rb[k_+6];                                \
        m1v[k_]  = tW[0]*(a0_+a4_) + tW[1]*(a1_+a3_) + tW[2]*a2_;              \
        m2v[k_]  = tW[0]*(b0_+b4_) + tW[1]*(b1_+b3_) + tW[2]*b2_;              \
        const float qp0 = a0_*a0_ + b0_*b0_ + a4_*a4_ + b4_*b4_;               \
        const float qp1 = a1_*a1_ + b1_*b1_ + a3_*a3_ + b3_*b3_;               \
        const float qp2 = a2_*a2_ + b2_*b2_;                                   \
        qsv[k_]  = tW[0]*qp0 + tW[1]*qp1 + tW[2]*qp2;                          \
        const float pp0 = a0_*b0_ + a4_*b4_;                                   \
        const float pp1 = a1_*b1_ + a3_*b3_;                                   \
        q12v[k_] = tW[0]*pp0 + tW[1]*pp1 + tW[2]*(a2_*b2_);                    \
    }                                                                          \
    /* fence: prior phase's intra-wave LDS reads ordered before these writes;  \
       HW processes a wave's DS ops in issue order. Also the scheduling fence  \
       that prevents cross-phase load-hoist spills (r4-r6 lesson). */          \
    asm volatile("" ::: "memory");                                             \
    *(float4*)&sP[0][wrow][c0 + 0][0] = make_float4(m1v[0],m2v[0],m1v[1],m2v[1]); \
    *(float4*)&sP[0][wrow][c0 + 2][0] = make_float4(m1v[2],m2v[2],m1v[3],m2v[3]); \
    *(float4*)&sP[1][wrow][c0 + 0][0] = make_float4(qsv[0],q12v[0],qsv[1],q12v[1]);\
    *(float4*)&sP[1][wrow][c0 + 2][0] = make_float4(qsv[2],q12v[2],qsv[3],q12v[3]);\
    asm volatile("" ::: "memory");  /* writes ordered before the reads below */\
    {                                                                          \
        /* H-conv, paired-plane reads: one b128 = both fields, both cols */    \
        const float4 p0r0 = *(const float4*)&sP[0][orow + 0][oc][0];           \
        const float4 p0r1 = *(const float4*)&sP[0][orow + 1][oc][0];           \
        const float4 p0r2 = *(const float4*)&sP[0][orow + 2][oc][0];           \
        const float4 p0r3 = *(const float4*)&sP[0][orow + 3][oc][0];           \
        const float4 p0r4 = *(const float4*)&sP[0][orow + 4][oc][0];           \
        const float4 p1r0 = *(const float4*)&sP[1][orow + 0][oc][0];           \
        const float4 p1r1 = *(const float4*)&sP[1][orow + 1][oc][0];           \
        const float4 p1r2 = *(const float4*)&sP[1][orow + 2][oc][0];           \
        const float4 p1r3 = *(const float4*)&sP[1][orow + 3][oc][0];           \
        const float4 p1r4 = *(const float4*)&sP[1][orow + 4][oc][0];           \
        /* layout per read: {f0[oc], f1[oc], f0[oc+1], f1[oc+1]} */            \
        ring[(P)][0].x = vW[0]*(p0r0.x+p0r4.x) + vW[1]*(p0r1.x+p0r3.x) + vW[2]*p0r2.x; \
        ring[(P)][0].y = vW[0]*(p0r0.z+p0r4.z) + vW[1]*(p0r1.z+p0r3.z) + vW[2]*p0r2.z; \
        ring[(P)][1].x = vW[0]*(p0r0.y+p0r4.y) + vW[1]*(p0r1.y+p0r3.y) + vW[2]*p0r2.y; \
        ring[(P)][1].y = vW[0]*(p0r0.w+p0r4.w) + vW[1]*(p0r1.w+p0r3.w) + vW[2]*p0r2.w; \
        ring[(P)][2].x = vW[0]*(p1r0.x+p1r4.x) + vW[1]*(p1r1.x+p1r3.x) + vW[2]*p1r2.x; \
        ring[(P)][2].y = vW[0]*(p1r0.z+p1r4.z) + vW[1]*(p1r1.z+p1r3.z) + vW[2]*p1r2.z; \
        ring[(P)][3].x = vW[0]*(p1r0.y+p1r4.y) + vW[1]*(p1r1.y+p1r3.y) + vW[2]*p1r2.y; \
        ring[(P)][3].y = vW[0]*(p1r0.w+p1r4.w) + vW[1]*(p1r1.w+p1r3.w) + vW[2]*p1r2.w; \
    }                                                                          \
    if (i_ >= 4) {                                                             \
        /* D-conv, symmetric: slots sA..sE = oldest..newest */                 \
        const int sA = ((P) + 1) % 5, sB = ((P) + 2) % 5, sC = ((P) + 3) % 5,  \
                  sD = ((P) + 4) % 5, sE = (P);                                \
        float2 F0, F1, F2, F3;                                                 \
        F0.x = uW[0]*(ring[sA][0].x+ring[sE][0].x)                             \
             + uW[1]*(ring[sB][0].x+ring[sD][0].x) + uW[2]*ring[sC][0].x;      \
        F0.y = uW[0]*(ring[sA][0].y+ring[sE][0].y)                             \
             + uW[1]*(ring[sB][0].y+ring[sD][0].y) + uW[2]*ring[sC][0].y;      \
        F1.x = uW[0]*(ring[sA][1].x+ring[sE][1].x)                             \
             + uW[1]*(ring[sB][1].x+ring[sD][1].x) + uW[2]*ring[sC][1].x;      \
        F1.y = uW[0]*(ring[sA][1].y+ring[sE][1].y)                             \
             + uW[1]*(ring[sB][1].y+ring[sD][1].y) + uW[2]*ring[sC][1].y;      \
        F2.x = uW[0]*(ring[sA][2].x+ring[sE][2].x)                             \
             + uW[1]*(ring[sB][2].x+ring[sD][2].x) + uW[2]*ring[sC][2].x;      \
        F2.y = uW[0]*(ring[sA][2].y+ring[sE][2].y)                             \
             + uW[1]*(ring[sB][2].y+ring[sD][2].y) + uW[2]*ring[sC][2].y;      \
        F3.x = uW[0]*(ring[sA][3].x+ring[sE][3].x)                             \
             + uW[1]*(ring[sB][3].x+ring[sD][3].x) + uW[2]*ring[sC][3].x;      \
        F3.y = uW[0]*(ring[sA][3].y+ring[sE][3].y)                             \
             + uW[1]*(ring[sB][3].y+ring[sD][3].y) + uW[2]*ring[sC][3].y;      \
        {                                                                      \
            const float mu1 = F0.x, mu2 = F1.x;                                \
            const float m11 = mu1*mu1, m22 = mu2*mu2, m12 = mu1*mu2;           \
            const float ms  = m11 + m22;                                       \
            const float num = (2.f*m12 + 1e-4f) * (2.f*(F3.x - m12) + 9e-4f);  \
            const float den = (ms + 1e-4f) * ((F2.x - ms) + 9e-4f);            \
            accS.x += __fdividef(num, den);                                    \
        }                                                                      \
        {                                                                      \
            const float mu1 = F0.y, mu2 = F1.y;                                \
            const float m11 = mu1*mu1, m22 = mu2*mu2, m12 = mu1*mu2;           \
            const float ms  = m11 + m22;                                       \
            const float num = (2.f*m12 + 1e-4f) * (2.f*(F3.y - m12) + 9e-4f);  \
            const float den = (ms + 1e-4f) * ((F2.y - ms) + 9e-4f);            \
            accS.y += __fdividef(num, den);                                    \
        }                                                                      \
    }                                                                          \
} while (0)

    // 12 slices: d0-2 .. d0+9. Proven 5-phase loop region x2 + 2-phase tail.
    for (int io = 0; io < 2; ++io) {
        const int ib = io * 5;
        PHASE(ib + 0, 0);
        PHASE(ib + 1, 1);
        PHASE(ib + 2, 2);
        PHASE(ib + 3, 3);
        PHASE(ib + 4, 4);
    }
    PHASE(10, 0);
    PHASE(11, 1);
#undef PHASE

    float acc = accS.x + accS.y;
    #pragma unroll
    for (int off = 32; off > 0; off >>= 1)
        acc += __shfl_down(acc, off, 64);
    __syncthreads();                     // only cross-wave sync in the kernel
    if (lane == 0) sRed[wv] = acc;
    __syncthreads();
    if (tid == 0) partials[bid] = sRed[0] + sRed[1] + sRed[2] + sRed[3];
}

__global__ void finalize_kernel(const float* __restrict__ partials, float* __restrict__ out) {
    const int tid = threadIdx.x;
    double s = 0.0;
    for (int i = tid; i < NBLK; i += 256) s += (double)partials[i];
    #pragma unroll
    for (int off = 32; off > 0; off >>= 1)
        s += __shfl_down(s, off, 64);
    __shared__ double sm[4];
    if ((tid & 63) == 0) sm[tid >> 6] = s;
    __syncthreads();
    if (tid == 0)
        out[0] = 1.0f - (float)((sm[0] + sm[1] + sm[2] + sm[3]) / (double)(4LL * 128 * 128 * 128));
}

extern "C" void kernel_launch(void* const* d_in, const int* in_sizes, int n_in,
                              void* d_out, int out_size, void* d_ws, size_t ws_size,
                              hipStream_t stream) {
    const float* img1 = (const float*)d_in[0];   // (4,2,128,128,128) fp32
    const float* img2 = (const float*)d_in[1];   // (4,1,128,128,128) fp32
    const float* win  = (const float*)d_in[2];   // (1,1,5,5,5) fp32
    float* out = (float*)d_out;
    float* ws  = (float*)d_ws;
    float* partials = ws;         // NBLK floats, fully rewritten every launch

    hipLaunchKernelGGL(ssim_main, dim3(NBLK), dim3(256), 0, stream, img1, img2, win, partials);
    hipLaunchKernelGGL(finalize_kernel, dim3(1), dim3(256), 0, stream, partials, out);
}

// Round 15
// 147.107 us; speedup vs baseline: 1.0535x; 1.0535x over previous
//
#include <hip/hip_runtime.h>

// SSIM 3D, round 18 = round 16 EXACTLY (best verified: main ~57 µs, wall
// 151.6, VGPR 56, 0 bank conflicts) + r17's one harmless piece kept:
// factorize_window fused into ssim_main (2 launches).
// r17 post-mortem: paired-plane b128 LDS reads traded 10 DS ops for 7.08M
// bank conflicts (row stride 264 ≡ 8 banks; orow x col-pair aliasing) ->
// main +6 µs. Lesson: the remaining ~33% VALU idle is CHAIN LATENCY, not
// DS-op count; r16's float4-write/float2-read layout with 0 conflicts is the
// right shape. Reverted verbatim.
// Structure (all session-verified):
//  - 4-field pipeline (m1, m2, qs=q11+q22, q12) — algebraic reduction;
//  - symmetric window: 9 weights, pair-sum taps in W/H/D;
//  - barrier-free wave-private LDS (wave owns 8 W-rows x 32-col stripe),
//    asm memory fences at the two former barrier sites (anti-hoist guard);
//  - DSUB=8, 2048 blocks x 4 waves = 32 waves/CU = HW max residency;
//  - 2x5-phase loop + 2-phase tail; plain partials tail; (256,2).
// Tripwires: VGPR ~56, conflicts ~0, WRITE_SIZE < 1 MB. If reproduced ->
// declare practical ceiling (TLP maxed, 0 barriers/conflicts/spills,
// algebra minimal; residual idle = intra-wave serial chain).
// Tile: W=128 (4 waves x 32 cols), TH=4 rows, DSUB=8 -> 2048 blocks.

#define NDIM 128
#define TH 4
#define WR (TH + 4)            // 8 W-conv rows
#define DSUB 8
#define NHT (NDIM / TH)        // 32
#define NDT (NDIM / DSUB)      // 16
#define NB 4
#define NBLK (NHT * NDT * NB)  // 2048

__launch_bounds__(256, 2)
__global__ void ssim_main(const float* __restrict__ img1,
                          const float* __restrict__ img2,
                          const float* __restrict__ win,
                          float* __restrict__ partials) {
    const int bid = blockIdx.x;
    const int th = bid % NHT;
    const int td = (bid / NHT) % NDT;
    const int b  = bid / (NHT * NDT);

    const int h0 = th * TH, d0 = td * DSUB;
    const float* __restrict__ x1 = img1 + (size_t)(b * 2 + 1) * NDIM * NDIM * NDIM;
    const float* __restrict__ x2 = img2 + (size_t)b * NDIM * NDIM * NDIM;

    // Symmetric rank-1 window factors, computed per block (wave-uniform,
    // bit-identical to the old factorize kernel; taps 3,4 == 1,0).
    const float w000 = win[0];
    float uW[3], vW[3], tW[3];
    #pragma unroll
    for (int i = 0; i < 3; ++i) {
        uW[i] = win[i * 25];
        vW[i] = win[i * 5] / w000;
        tW[i] = win[i] / w000;
    }

    __shared__ float sWc[4][WR][NDIM];   // 16 KB; wave w uses cols [32w,32w+32)
    __shared__ float sRed[4];

    const int tid  = threadIdx.x;
    const int wv   = tid >> 6;           // wave id 0..3 -> col stripe
    const int lane = tid & 63;
    const int sc   = wv * 32;            // stripe col base
    // W-conv mapping (per wave): 8 rows x 8 col-groups of 4
    const int wrow = lane >> 3;          // 0..7
    const int wg   = lane & 7;           // 0..7
    const int c0   = sc + wg * 4;        // global col of this lane's 4 outputs
    const int ghw  = h0 + wrow - 2;
    // H/D mapping (per wave): 4 rows x 16 col-pairs of 2
    const int orow = lane >> 4;          // 0..3
    const int oc   = sc + (lane & 15) * 2;

    float2 ring[5][4];                   // [slot][field: m1,m2,qs,q12]
    float2 accS = make_float2(0.f, 0.f);

#define PHASE(I, P) do {                                                       \
    const int i_ = (I);                                                        \
    const int d_ = d0 - 2 + i_;                                                \
    float4 A0 = make_float4(0,0,0,0), A1 = A0, A2 = A0;                        \
    float4 B0 = A0, B1 = A0, B2 = A0;                                          \
    if (((unsigned)d_ < NDIM) && ((unsigned)ghw < NDIM)) {                     \
        const float* __restrict__ r1_ = x1 + ((size_t)d_ * NDIM + ghw) * NDIM; \
        const float* __restrict__ r2_ = x2 + ((size_t)d_ * NDIM + ghw) * NDIM; \
        if (c0 > 0)   { A0 = *(const float4*)(r1_ + c0 - 4);                   \
                        B0 = *(const float4*)(r2_ + c0 - 4); }                 \
        A1 = *(const float4*)(r1_ + c0);                                       \
        B1 = *(const float4*)(r2_ + c0);                                       \
        if (c0 < 124) { A2 = *(const float4*)(r1_ + c0 + 4);                   \
                        B2 = *(const float4*)(r2_ + c0 + 4); }                 \
    }                                                                          \
    float ra[12] = {A0.x,A0.y,A0.z,A0.w, A1.x,A1.y,A1.z,A1.w,                  \
                    A2.x,A2.y,A2.z,A2.w};                                      \
    float rb[12] = {B0.x,B0.y,B0.z,B0.w, B1.x,B1.y,B1.z,B1.w,                  \
                    B2.x,B2.y,B2.z,B2.w};                                      \
    float m1v[4], m2v[4], qsv[4], q12v[4];                                     \
    _Pragma("unroll")                                                          \
    for (int k_ = 0; k_ < 4; ++k_) {                                           \
        const float a0_=ra[k_+2], a1_=ra[k_+3], a2_=ra[k_+4],                  \
                    a3_=ra[k_+5], a4_=ra[k_+6];                                \
        const float b0_=rb[k_+2], b1_=rb[k_+3], b2_=rb[k_+4],                  \
                    b3_=rb[k_+5], b4_=rb[k_+6];                                \
        /* symmetric taps: tW[0]*(x0+x4) + tW[1]*(x1+x3) + tW[2]*x2 */         \
        m1v[k_]  = tW[0]*(a0_+a4_) + tW[1]*(a1_+a3_) + tW[2]*a2_;              \
        m2v[k_]  = tW[0]*(b0_+b4_) + tW[1]*(b1_+b3_) + tW[2]*b2_;              \
        const float qp0 = a0_*a0_ + b0_*b0_ + a4_*a4_ + b4_*b4_;               \
        const float qp1 = a1_*a1_ + b1_*b1_ + a3_*a3_ + b3_*b3_;               \
        const float qp2 = a2_*a2_ + b2_*b2_;                                   \
        qsv[k_]  = tW[0]*qp0 + tW[1]*qp1 + tW[2]*qp2;                          \
        const float pp0 = a0_*b0_ + a4_*b4_;                                   \
        const float pp1 = a1_*b1_ + a3_*b3_;                                   \
        q12v[k_] = tW[0]*pp0 + tW[1]*pp1 + tW[2]*(a2_*b2_);                    \
    }                                                                          \
    /* fence: prior phase's intra-wave LDS reads ordered before these writes;  \
       HW processes a wave's DS ops in issue order. Also the scheduling fence  \
       that prevents cross-phase load-hoist spills (r4-r6 lesson). */          \
    asm volatile("" ::: "memory");                                             \
    *(float4*)&sWc[0][wrow][c0] = make_float4(m1v[0],m1v[1],m1v[2],m1v[3]);    \
    *(float4*)&sWc[1][wrow][c0] = make_float4(m2v[0],m2v[1],m2v[2],m2v[3]);    \
    *(float4*)&sWc[2][wrow][c0] = make_float4(qsv[0],qsv[1],qsv[2],qsv[3]);    \
    *(float4*)&sWc[3][wrow][c0] = make_float4(q12v[0],q12v[1],q12v[2],q12v[3]);\
    asm volatile("" ::: "memory");  /* writes ordered before the reads below */\
    _Pragma("unroll")                                                          \
    for (int f_ = 0; f_ < 4; ++f_) {                                           \
        const float2 r0_ = *(const float2*)&sWc[f_][orow + 0][oc];             \
        const float2 r1_ = *(const float2*)&sWc[f_][orow + 1][oc];             \
        const float2 r2_ = *(const float2*)&sWc[f_][orow + 2][oc];             \
        const float2 r3_ = *(const float2*)&sWc[f_][orow + 3][oc];             \
        const float2 r4_ = *(const float2*)&sWc[f_][orow + 4][oc];             \
        float2 F_;                                                             \
        F_.x = vW[0]*(r0_.x+r4_.x) + vW[1]*(r1_.x+r3_.x) + vW[2]*r2_.x;        \
        F_.y = vW[0]*(r0_.y+r4_.y) + vW[1]*(r1_.y+r3_.y) + vW[2]*r2_.y;        \
        ring[(P)][f_] = F_;                                                    \
    }                                                                          \
    if (i_ >= 4) {                                                             \
        /* D-conv, symmetric: slots sA..sE = oldest..newest */                 \
        const int sA = ((P) + 1) % 5, sB = ((P) + 2) % 5, sC = ((P) + 3) % 5,  \
                  sD = ((P) + 4) % 5, sE = (P);                                \
        float2 F0, F1, F2, F3;                                                 \
        F0.x = uW[0]*(ring[sA][0].x+ring[sE][0].x)                             \
             + uW[1]*(ring[sB][0].x+ring[sD][0].x) + uW[2]*ring[sC][0].x;      \
        F0.y = uW[0]*(ring[sA][0].y+ring[sE][0].y)                             \
             + uW[1]*(ring[sB][0].y+ring[sD][0].y) + uW[2]*ring[sC][0].y;      \
        F1.x = uW[0]*(ring[sA][1].x+ring[sE][1].x)                             \
             + uW[1]*(ring[sB][1].x+ring[sD][1].x) + uW[2]*ring[sC][1].x;      \
        F1.y = uW[0]*(ring[sA][1].y+ring[sE][1].y)                             \
             + uW[1]*(ring[sB][1].y+ring[sD][1].y) + uW[2]*ring[sC][1].y;      \
        F2.x = uW[0]*(ring[sA][2].x+ring[sE][2].x)                             \
             + uW[1]*(ring[sB][2].x+ring[sD][2].x) + uW[2]*ring[sC][2].x;      \
        F2.y = uW[0]*(ring[sA][2].y+ring[sE][2].y)                             \
             + uW[1]*(ring[sB][2].y+ring[sD][2].y) + uW[2]*ring[sC][2].y;      \
        F3.x = uW[0]*(ring[sA][3].x+ring[sE][3].x)                             \
             + uW[1]*(ring[sB][3].x+ring[sD][3].x) + uW[2]*ring[sC][3].x;      \
        F3.y = uW[0]*(ring[sA][3].y+ring[sE][3].y)                             \
             + uW[1]*(ring[sB][3].y+ring[sD][3].y) + uW[2]*ring[sC][3].y;      \
        {                                                                      \
            const float mu1 = F0.x, mu2 = F1.x;                                \
            const float m11 = mu1*mu1, m22 = mu2*mu2, m12 = mu1*mu2;           \
            const float ms  = m11 + m22;                                       \
            const float num = (2.f*m12 + 1e-4f) * (2.f*(F3.x - m12) + 9e-4f);  \
            const float den = (ms + 1e-4f) * ((F2.x - ms) + 9e-4f);            \
            accS.x += __fdividef(num, den);                                    \
        }                                                                      \
        {                                                                      \
            const float mu1 = F0.y, mu2 = F1.y;                                \
            const float m11 = mu1*mu1, m22 = mu2*mu2, m12 = mu1*mu2;           \
            const float ms  = m11 + m22;                                       \
            const float num = (2.f*m12 + 1e-4f) * (2.f*(F3.y - m12) + 9e-4f);  \
            const float den = (ms + 1e-4f) * ((F2.y - ms) + 9e-4f);            \
            accS.y += __fdividef(num, den);                                    \
        }                                                                      \
    }                                                                          \
} while (0)

    // 12 slices: d0-2 .. d0+9. Proven 5-phase loop region x2 + 2-phase tail.
    for (int io = 0; io < 2; ++io) {
        const int ib = io * 5;
        PHASE(ib + 0, 0);
        PHASE(ib + 1, 1);
        PHASE(ib + 2, 2);
        PHASE(ib + 3, 3);
        PHASE(ib + 4, 4);
    }
    PHASE(10, 0);
    PHASE(11, 1);
#undef PHASE

    float acc = accS.x + accS.y;
    #pragma unroll
    for (int off = 32; off > 0; off >>= 1)
        acc += __shfl_down(acc, off, 64);
    __syncthreads();                     // only cross-wave sync in the kernel
    if (lane == 0) sRed[wv] = acc;
    __syncthreads();
    if (tid == 0) partials[bid] = sRed[0] + sRed[1] + sRed[2] + sRed[3];
}

__global__ void finalize_kernel(const float* __restrict__ partials, float* __restrict__ out) {
    const int tid = threadIdx.x;
    double s = 0.0;
    for (int i = tid; i < NBLK; i += 256) s += (double)partials[i];
    #pragma unroll
    for (int off = 32; off > 0; off >>= 1)
        s += __shfl_down(s, off, 64);
    __shared__ double sm[4];
    if ((tid & 63) == 0) sm[tid >> 6] = s;
    __syncthreads();
    if (tid == 0)
        out[0] = 1.0f - (float)((sm[0] + sm[1] + sm[2] + sm[3]) / (double)(4LL * 128 * 128 * 128));
}

extern "C" void kernel_launch(void* const* d_in, const int* in_sizes, int n_in,
                              void* d_out, int out_size, void* d_ws, size_t ws_size,
                              hipStream_t stream) {
    const float* img1 = (const float*)d_in[0];   // (4,2,128,128,128) fp32
    const float* img2 = (const float*)d_in[1];   // (4,1,128,128,128) fp32
    const float* win  = (const float*)d_in[2];   // (1,1,5,5,5) fp32
    float* out = (float*)d_out;
    float* ws  = (float*)d_ws;
    float* partials = ws;         // NBLK floats, fully rewritten every launch

    hipLaunchKernelGGL(ssim_main, dim3(NBLK), dim3(256), 0, stream, img1, img2, win, partials);
    hipLaunchKernelGGL(finalize_kernel, dim3(1), dim3(256), 0, stream, partials, out);
}